// Round 27
// baseline (84.643 us; speedup 1.0000x reference)
//
#include <hip/hip_runtime.h>

#define Bq 8
#define Tq 64
#define Sq 256
#define Hq 768
#define TT 8
#define ST 16

typedef float f32x4 __attribute__((ext_vector_type(4)));
typedef __bf16 bf16x8 __attribute__((ext_vector_type(8)));

#define TANH_SCALE 2.885390081777927f   // 2*log2(e): exp2(u*TS) = e^{2u}
#define LOG2E 1.4426950408889634f

// ---- DPP reduction -----------------------------------------------------------
template <int Ctrl, int Rmask>
__device__ __forceinline__ float dpp_add_f(float v) {
  int t = __builtin_amdgcn_update_dpp(0, __float_as_int(v), Ctrl, Rmask, 0xF, true);
  return v + __int_as_float(t);
}
__device__ __forceinline__ float wave64_sum(float v) {
  v = dpp_add_f<0xB1, 0xF>(v);
  v = dpp_add_f<0x4E, 0xF>(v);
  v = dpp_add_f<0x141, 0xF>(v);
  v = dpp_add_f<0x140, 0xF>(v);
  v = dpp_add_f<0x142, 0xA>(v);
  v = dpp_add_f<0x143, 0xC>(v);
  return __int_as_float(__builtin_amdgcn_readlane(__float_as_int(v), 63));
}

__device__ __forceinline__ uint2 cvt4(f32x4 v) {
  union { __bf16 h[4]; uint2 u; } t;
  t.h[0] = (__bf16)v[0]; t.h[1] = (__bf16)v[1];
  t.h[2] = (__bf16)v[2]; t.h[3] = (__bf16)v[3];
  return t.u;
}

// ---------------- projection GEMMs (r23-proven, ~12us) ------------------------
__global__ __launch_bounds__(256, 4) void proj_kernel(
    const float* __restrict__ enc, const float* __restrict__ dec,
    const float* __restrict__ Wh, const float* __restrict__ Wd,
    const float* __restrict__ bd,
    const float* __restrict__ wcvec, const float* __restrict__ vvec,
    __bf16* __restrict__ efh, __bf16* __restrict__ decfh,
    float* __restrict__ w1g, float* __restrict__ lacc,
    unsigned* __restrict__ cnt, unsigned* __restrict__ chunkflag,
    unsigned* __restrict__ sflag)
{
  {
    int gidx = blockIdx.x * 256 + threadIdx.x;
    if (gidx < Hq) w1g[gidx] = vvec[gidx] * wcvec[gidx];
    if (gidx < 64) { cnt[gidx] = 0u; chunkflag[gidx] = 0u; }
    if (gidx < Bq) sflag[gidx] = 0u;
    if (gidx == 0) lacc[0] = 0.f;
  }

  __shared__ unsigned short As[2][32][40];
  __shared__ unsigned short Bs[2][64][40];

  int bid = blockIdx.x;
  const float* A; const float* W; bool isEf;
  int bm, bn;
  if (bid < 768) {
    A = enc; W = Wh; isEf = true;
    bm = bid % 64; bn = bid / 64;               // XCD affinity via bm%8
  } else {
    bid -= 768;
    A = dec; W = Wd; isEf = false;
    bm = bid % 16; bn = bid / 16;
  }
  const int m0 = bm * 32, n0 = bn * 64;

  const int ti = threadIdx.x;
  const int rowA = ti >> 3, colA = (ti & 7) * 4;
  const int rowB = ti >> 2, colB = (ti & 3) * 8;
  const float* pa = A + (size_t)(m0 + rowA) * Hq + colA;
  const float* pw = W + (size_t)(n0 + rowB) * Hq + colB;

  {
    f32x4 a0 = *(const f32x4*)pa;
    f32x4 w0 = *(const f32x4*)pw, w1 = *(const f32x4*)(pw + 4);
    *(uint2*)&As[0][rowA][colA]     = cvt4(a0);
    *(uint2*)&Bs[0][rowB][colB]     = cvt4(w0);
    *(uint2*)&Bs[0][rowB][colB + 4] = cvt4(w1);
  }
  __syncthreads();

  const int w = ti >> 6, ln = ti & 63;
  const int mh = (w >> 1) * 16, nh = (w & 1) * 32;
  const int rsel = ln & 15, kofe = (ln >> 4) * 8;

  f32x4 acc[2] = {};
  for (int k = 0; k < 24; k++) {
    f32x4 na, nw0, nw1;
    if (k < 23) {
      na  = *(const f32x4*)(pa + (k + 1) * 32);
      nw0 = *(const f32x4*)(pw + (k + 1) * 32);
      nw1 = *(const f32x4*)(pw + (k + 1) * 32 + 4);
    }
    const int cur = k & 1;
    bf16x8 af = *(const bf16x8*)&As[cur][mh + rsel][kofe];
    bf16x8 b0 = *(const bf16x8*)&Bs[cur][nh + rsel][kofe];
    bf16x8 b1 = *(const bf16x8*)&Bs[cur][nh + 16 + rsel][kofe];
    acc[0] = __builtin_amdgcn_mfma_f32_16x16x32_bf16(af, b0, acc[0], 0, 0, 0);
    acc[1] = __builtin_amdgcn_mfma_f32_16x16x32_bf16(af, b1, acc[1], 0, 0, 0);
    if (k < 23) {
      const int nxt = cur ^ 1;
      *(uint2*)&As[nxt][rowA][colA]     = cvt4(na);
      *(uint2*)&Bs[nxt][rowB][colB]     = cvt4(nw0);
      *(uint2*)&Bs[nxt][rowB][colB + 4] = cvt4(nw1);
      __syncthreads();
    }
  }

  const int col = ln & 15, rb = (ln >> 4) * 4;
#pragma unroll
  for (int tn = 0; tn < 2; tn++)
#pragma unroll
    for (int j = 0; j < 4; j++) {
      int r = m0 + mh + rb + j, c = n0 + nh + tn * 16 + col;
      float val = acc[tn][j];
      if (isEf) {
        efh[(size_t)r * Hq + c] =
            (__bf16)__builtin_amdgcn_exp2f(val * TANH_SCALE);
      } else {
        decfh[(size_t)r * Hq + c] =
            (__bf16)__builtin_amdgcn_exp2f((val + bd[c]) * TANH_SCALE);
      }
    }
}

// ---------------- fused AB + single-wave scan + ht ----------------------------
// 1224 blocks: 0..1023 AB tiles; 1024..1031 scan (1 wave); 1032..1223 ht.
// Unconditionally deadlock-free: spinners (<=200) cannot starve AB (AB blocks
// depend on nothing and retire, cycling through the >=824 remaining slots),
// then scan's cnt flags are satisfiable, then ht's chunk flags.
// Handoffs: relaxed agent atomics via IC only (r20-proven). Scan attn stores
// are fire-and-forget relaxed atomics; ONE vmcnt(0) per 8-step chunk before
// the chunkflag store (no per-step drain — the r23 trap).
__global__ __launch_bounds__(256, 4) void abscanht_kernel(
    const __bf16* __restrict__ efh, const __bf16* __restrict__ decfh,
    const float* __restrict__ vvec, const float* __restrict__ w1g,
    const float* __restrict__ emask, const float* __restrict__ cov0,
    const float* __restrict__ dmask, const float* __restrict__ enc,
    float2* __restrict__ ab,
    float* __restrict__ out_attn, float* __restrict__ out_covf,
    float* __restrict__ out_ht, float* __restrict__ out_loss,
    float* __restrict__ lacc, unsigned* __restrict__ cnt,
    unsigned* __restrict__ chunkflag, unsigned* __restrict__ sflag)
{
  __shared__ double smem_raw[4808];           // 38464 B (max over paths)
  const int bid = blockIdx.x;
  const int tid = threadIdx.x;

  if (bid < 1024) {
    // -------- AB tile (r25-proven) --------
    unsigned short (*efs)[780] = (unsigned short(*)[780])smem_raw;
    unsigned short (*dts)[776] = (unsigned short(*)[776])((char*)smem_raw + 24960);
    float (*part)[2]           = (float(*)[2])((char*)smem_raw + 37376);
    const int b = bid & 7;
    const int r = bid >> 3;                   // 0..127
    const int kchunk = r & 7;
    const int tt0 = kchunk * TT;
    const int st0 = (r >> 3) * ST;

    for (int i = tid; i < ST * 192; i += 256) {
      int row = i / 192, c = (i % 192) * 4;
      *(uint2*)&efs[row][c] =
          *(const uint2*)(efh + (size_t)(b * Sq + st0 + row) * Hq + c);
    }
    for (int i = tid; i < TT * 192; i += 256) {
      int row = i / 192, c = (i % 192) * 4;
      *(uint2*)&dts[row][c] =
          *(const uint2*)(decfh + (size_t)(b * Tq + tt0 + row) * Hq + c);
    }
    __syncthreads();

    const int hh = tid >> 7;
    const int pid = tid & 127;
    const int tl = pid >> 4, sl = pid & 15;
    const int hbase = hh * 384;
    const int hbu = __builtin_amdgcn_readfirstlane(hbase);
    const float* vp  = vvec + hbu;
    const float* w1p = w1g + hbu;

    float A = 0.f, B = 0.f;
#define BLO(x) __uint_as_float((x) << 16)
#define BHI(x) __uint_as_float((x) & 0xFFFF0000u)
#pragma unroll 4
    for (int j = 0; j < 384; j += 4) {
      uint2 eu = *(const uint2*)&efs[sl][hbase + j];
      uint2 du = *(const uint2*)&dts[tl][hbase + j];
      f32x4 v4 = *(const f32x4*)(vp + j);
      f32x4 w1 = *(const f32x4*)(w1p + j);
      float e2[4];
      e2[0] = BLO(eu.x) * BLO(du.x);
      e2[1] = BHI(eu.x) * BHI(du.x);
      e2[2] = BLO(eu.y) * BLO(du.y);
      e2[3] = BHI(eu.y) * BHI(du.y);
#pragma unroll
      for (int e = 0; e < 4; e++) {
        float rr = __builtin_amdgcn_rcpf(1.f + e2[e]);
        float t0 = 1.f - 2.f * rr;
        float f1 = 1.f - t0 * t0;
        A += v4[e] * t0;
        B += w1[e] * f1;
      }
    }
#undef BLO
#undef BHI

    if (hh == 1) { part[pid][0] = A; part[pid][1] = B; }
    __syncthreads();
    if (hh == 0) {
      union { float2 f; unsigned long long u; } cv;
      cv.f.x = A + part[pid][0];
      cv.f.y = B + part[pid][1];
      __hip_atomic_store(
          (unsigned long long*)&ab[(size_t)(b * Tq + tt0 + tl) * Sq + st0 + sl],
          cv.u, __ATOMIC_RELAXED, __HIP_MEMORY_SCOPE_AGENT);
    }
    __syncthreads();   // drains ab stores (vmcnt(0) pre-barrier)
    if (tid == 0)
      __hip_atomic_fetch_add(&cnt[b * 8 + kchunk], 1u,
                             __ATOMIC_RELAXED, __HIP_MEMORY_SCOPE_AGENT);
  } else if (bid < 1032) {
    // -------- single-wave scan (batch b) --------
    if (tid >= 64) return;
    const int b = bid - 1024;
    const int ln = tid;
    float dm = dmask[b * Tq + ln];
    float cov[4], em[4], E[4];
    float lp = 0.f;
#pragma unroll
    for (int i = 0; i < 4; i++) {
      cov[i] = cov0[b * Sq + ln + 64 * i];
      em[i]  = emask[b * Sq + ln + 64 * i];
    }
    const unsigned long long* P =
        (const unsigned long long*)(ab + (size_t)b * Tq * Sq + ln);
    union U64 { unsigned long long u; float2 f; };
    U64 cv0[4], cv1[4];

    for (int kc = 0; kc < 8; kc++) {
      unsigned c;
      do {
        c = __hip_atomic_load(&cnt[b * 8 + kc],
                              __ATOMIC_RELAXED, __HIP_MEMORY_SCOPE_AGENT);
      } while (__builtin_amdgcn_readfirstlane(c) < 16u);

      const int tb = kc * 8;
#pragma unroll
      for (int i = 0; i < 4; i++)
        cv0[i].u = __hip_atomic_load(P + (size_t)tb * Sq + 64 * i,
                                     __ATOMIC_RELAXED, __HIP_MEMORY_SCOPE_AGENT);
#pragma unroll
      for (int i = 0; i < 4; i++)
        cv1[i].u = __hip_atomic_load(P + (size_t)(tb + 1) * Sq + 64 * i,
                                     __ATOMIC_RELAXED, __HIP_MEMORY_SCOPE_AGENT);

#pragma unroll
      for (int j = 0; j < 8; j++) {
        const int t = tb + j;
        float s4 = 0.f;
#pragma unroll
        for (int i = 0; i < 4; i++) {
          float sc = cv0[i].f.x + cov[i] * cv0[i].f.y;
          E[i] = __builtin_amdgcn_exp2f(sc * LOG2E) * em[i];
          s4 += E[i];
        }
#pragma unroll
        for (int i = 0; i < 4; i++) {
          cv0[i] = cv1[i];
          if (j < 6)
            cv1[i].u = __hip_atomic_load(P + (size_t)(t + 2) * Sq + 64 * i,
                                         __ATOMIC_RELAXED, __HIP_MEMORY_SCOPE_AGENT);
        }
        float Z = wave64_sum(s4);
        float invZ = __builtin_amdgcn_rcpf(Z);
        float dmt = __shfl(dm, t);
#pragma unroll
        for (int i = 0; i < 4; i++) {
          float at = E[i] * invZ;
          lp += fminf(at, cov[i]) * dmt;
          cov[i] += at;
          __hip_atomic_store(&out_attn[(size_t)(b * Tq + t) * Sq + ln + 64 * i],
                             at, __ATOMIC_RELAXED, __HIP_MEMORY_SCOPE_AGENT);
        }
      }
      // chunk done: one drain, then publish (stores reached the IC)
      asm volatile("s_waitcnt vmcnt(0)" ::: "memory");
      if (ln == 0)
        __hip_atomic_store(&chunkflag[b * 8 + kc], 1u,
                           __ATOMIC_RELAXED, __HIP_MEMORY_SCOPE_AGENT);
    }

#pragma unroll
    for (int i = 0; i < 4; i++)
      out_covf[b * Sq + ln + 64 * i] = cov[i];
    float wl = wave64_sum(lp);
    if (ln == 0) {
      atomicAdd(lacc, wl);
      asm volatile("s_waitcnt vmcnt(0)" ::: "memory");
      __hip_atomic_store(&sflag[b], 1u,
                         __ATOMIC_RELAXED, __HIP_MEMORY_SCOPE_AGENT);
    }
  } else {
    // -------- ht tile (waits only on its own chunk) --------
    float (*lat)[8] = (float(*)[8])smem_raw;  // [256][8]
    float* r4 = (float*)smem_raw + 2048;
    const int hidx = bid - 1032;              // 0..191
    const int b = hidx / 24, r2 = hidx % 24, tc = r2 / 3, hc = r2 % 3;
    if (tid == 0)
      while (__hip_atomic_load(&chunkflag[b * 8 + tc],
                               __ATOMIC_RELAXED, __HIP_MEMORY_SCOPE_AGENT) == 0u)
        __builtin_amdgcn_s_sleep(2);
    __syncthreads();

    const int h = hc * 256 + tid;
#pragma unroll
    for (int tt = 0; tt < 8; tt++)
      lat[tid][tt] = __hip_atomic_load(
          &out_attn[(size_t)(b * Tq + tc * 8 + tt) * Sq + tid],
          __ATOMIC_RELAXED, __HIP_MEMORY_SCOPE_AGENT);
    __syncthreads();

    float acc[8] = {};
    const float* ep = enc + (size_t)(b * Sq) * Hq + h;
    for (int sb = 0; sb < Sq; sb += 8) {
      float e[8];
#pragma unroll
      for (int u = 0; u < 8; u++) e[u] = ep[(size_t)(sb + u) * Hq];
#pragma unroll
      for (int u = 0; u < 8; u++) {
        f32x4 a0 = *(const f32x4*)&lat[sb + u][0];
        f32x4 a1 = *(const f32x4*)&lat[sb + u][4];
        acc[0] += a0[0] * e[u]; acc[1] += a0[1] * e[u];
        acc[2] += a0[2] * e[u]; acc[3] += a0[3] * e[u];
        acc[4] += a1[0] * e[u]; acc[5] += a1[1] * e[u];
        acc[6] += a1[2] * e[u]; acc[7] += a1[3] * e[u];
      }
    }
#pragma unroll
    for (int tt = 0; tt < 8; tt++)
      out_ht[(size_t)(b * Tq + tc * 8 + tt) * Hq + h] = acc[tt];

    if (hidx == 0) {
      if (tid == 0)
        for (int bb = 0; bb < Bq; bb++)
          while (__hip_atomic_load(&sflag[bb],
                                   __ATOMIC_RELAXED, __HIP_MEMORY_SCOPE_AGENT) == 0u)
            __builtin_amdgcn_s_sleep(2);
      __syncthreads();
      float ssum = 0.f;
      for (int i = tid; i < Bq * Tq; i += 256) ssum += dmask[i];
#pragma unroll
      for (int off = 32; off; off >>= 1) ssum += __shfl_xor(ssum, off);
      int w = tid >> 6, ln = tid & 63;
      if (ln == 0) r4[w] = ssum;
      __syncthreads();
      if (tid == 0)
        out_loss[0] = __hip_atomic_load(lacc, __ATOMIC_RELAXED,
                                        __HIP_MEMORY_SCOPE_AGENT)
                      / (r4[0] + r4[1] + r4[2] + r4[3]);
    }
  }
}

extern "C" void kernel_launch(void* const* d_in, const int* in_sizes, int n_in,
                              void* d_out, int out_size, void* d_ws, size_t ws_size,
                              hipStream_t stream) {
  const float* dec   = (const float*)d_in[0];   // [8,64,768]
  const float* dmask = (const float*)d_in[1];   // [8,64]
  const float* enc   = (const float*)d_in[2];   // [8,256,768]
  const float* emask = (const float*)d_in[3];   // [8,256]
  const float* cov0  = (const float*)d_in[4];   // [8,256]
  const float* Wh    = (const float*)d_in[5];   // [768,768]
  const float* Wd    = (const float*)d_in[6];   // [768,768]
  const float* bd    = (const float*)d_in[7];   // [768]
  const float* wc    = (const float*)d_in[8];   // [768]
  const float* vv    = (const float*)d_in[9];   // [768]
  float* out = (float*)d_out;

  char* ws = (char*)d_ws;
  __bf16*   efh   = (__bf16*)ws;                 // 3145728 B
  __bf16*   decfh = (__bf16*)(ws + 3145728);     // 786432 B
  float2*   ab    = (float2*)(ws + 3932160);     // 1048576 B
  float*    w1g   = (float*)(ws + 4980736);      // 3072 B
  float*    lacc  = (float*)(ws + 4983808);      // 4 B
  unsigned* cnt   = (unsigned*)(ws + 4983872);   // 256 B
  unsigned* chunkflag = (unsigned*)(ws + 4984128); // 256 B
  unsigned* sflag = (unsigned*)(ws + 4984384);   // 32 B

  const size_t OFF_ATTN = (size_t)Bq * Tq * Hq;             // 393216
  const size_t OFF_LOSS = OFF_ATTN + (size_t)Bq * Tq * Sq;  // 524288
  const size_t OFF_COV  = OFF_LOSS + 1;                     // 524289

  proj_kernel<<<960, 256, 0, stream>>>(enc, dec, Wh, Wd, bd, wc, vv,
                                       efh, decfh, w1g, lacc,
                                       cnt, chunkflag, sflag);
  abscanht_kernel<<<1224, 256, 0, stream>>>(efh, decfh, vv, w1g, emask, cov0,
                                            dmask, enc, ab,
                                            out + OFF_ATTN, out + OFF_COV,
                                            out, out + OFF_LOSS, lacc,
                                            cnt, chunkflag, sflag);
}

// Round 28
// 80.804 us; speedup vs baseline: 1.0475x; 1.0475x over previous
//
#include <hip/hip_runtime.h>

#define Bq 8
#define Tq 64
#define Sq 256
#define Hq 768
#define TT 8
#define ST 16

typedef float f32x4 __attribute__((ext_vector_type(4)));
typedef __bf16 bf16x8 __attribute__((ext_vector_type(8)));

#define TANH_SCALE 2.885390081777927f   // 2*log2(e): exp2(u*TS) = e^{2u}
#define LOG2E 1.4426950408889634f

// ---- DPP reduction -----------------------------------------------------------
template <int Ctrl, int Rmask>
__device__ __forceinline__ float dpp_add_f(float v) {
  int t = __builtin_amdgcn_update_dpp(0, __float_as_int(v), Ctrl, Rmask, 0xF, true);
  return v + __int_as_float(t);
}
__device__ __forceinline__ float wave64_sum(float v) {
  v = dpp_add_f<0xB1, 0xF>(v);
  v = dpp_add_f<0x4E, 0xF>(v);
  v = dpp_add_f<0x141, 0xF>(v);
  v = dpp_add_f<0x140, 0xF>(v);
  v = dpp_add_f<0x142, 0xA>(v);
  v = dpp_add_f<0x143, 0xC>(v);
  return __int_as_float(__builtin_amdgcn_readlane(__float_as_int(v), 63));
}

__device__ __forceinline__ uint2 cvt4(f32x4 v) {
  union { __bf16 h[4]; uint2 u; } t;
  t.h[0] = (__bf16)v[0]; t.h[1] = (__bf16)v[1];
  t.h[2] = (__bf16)v[2]; t.h[3] = (__bf16)v[3];
  return t.u;
}

// ---------------- projection GEMMs (r23-proven, ~12us) ------------------------
__global__ __launch_bounds__(256, 4) void proj_kernel(
    const float* __restrict__ enc, const float* __restrict__ dec,
    const float* __restrict__ Wh, const float* __restrict__ Wd,
    const float* __restrict__ bd,
    const float* __restrict__ wcvec, const float* __restrict__ vvec,
    __bf16* __restrict__ efh, __bf16* __restrict__ decfh,
    float* __restrict__ w1g, float* __restrict__ lacc,
    unsigned* __restrict__ cnt)
{
  {
    int gidx = blockIdx.x * 256 + threadIdx.x;
    if (gidx < Hq) w1g[gidx] = vvec[gidx] * wcvec[gidx];
    if (gidx < 64) cnt[gidx] = 0u;
    if (gidx == 0) lacc[0] = 0.f;
  }

  __shared__ unsigned short As[2][32][40];
  __shared__ unsigned short Bs[2][64][40];

  int bid = blockIdx.x;
  const float* A; const float* W; bool isEf;
  int bm, bn;
  if (bid < 768) {
    A = enc; W = Wh; isEf = true;
    bm = bid % 64; bn = bid / 64;               // XCD affinity via bm%8
  } else {
    bid -= 768;
    A = dec; W = Wd; isEf = false;
    bm = bid % 16; bn = bid / 16;
  }
  const int m0 = bm * 32, n0 = bn * 64;

  const int ti = threadIdx.x;
  const int rowA = ti >> 3, colA = (ti & 7) * 4;
  const int rowB = ti >> 2, colB = (ti & 3) * 8;
  const float* pa = A + (size_t)(m0 + rowA) * Hq + colA;
  const float* pw = W + (size_t)(n0 + rowB) * Hq + colB;

  {
    f32x4 a0 = *(const f32x4*)pa;
    f32x4 w0 = *(const f32x4*)pw, w1 = *(const f32x4*)(pw + 4);
    *(uint2*)&As[0][rowA][colA]     = cvt4(a0);
    *(uint2*)&Bs[0][rowB][colB]     = cvt4(w0);
    *(uint2*)&Bs[0][rowB][colB + 4] = cvt4(w1);
  }
  __syncthreads();

  const int w = ti >> 6, ln = ti & 63;
  const int mh = (w >> 1) * 16, nh = (w & 1) * 32;
  const int rsel = ln & 15, kofe = (ln >> 4) * 8;

  f32x4 acc[2] = {};
  for (int k = 0; k < 24; k++) {
    f32x4 na, nw0, nw1;
    if (k < 23) {
      na  = *(const f32x4*)(pa + (k + 1) * 32);
      nw0 = *(const f32x4*)(pw + (k + 1) * 32);
      nw1 = *(const f32x4*)(pw + (k + 1) * 32 + 4);
    }
    const int cur = k & 1;
    bf16x8 af = *(const bf16x8*)&As[cur][mh + rsel][kofe];
    bf16x8 b0 = *(const bf16x8*)&Bs[cur][nh + rsel][kofe];
    bf16x8 b1 = *(const bf16x8*)&Bs[cur][nh + 16 + rsel][kofe];
    acc[0] = __builtin_amdgcn_mfma_f32_16x16x32_bf16(af, b0, acc[0], 0, 0, 0);
    acc[1] = __builtin_amdgcn_mfma_f32_16x16x32_bf16(af, b1, acc[1], 0, 0, 0);
    if (k < 23) {
      const int nxt = cur ^ 1;
      *(uint2*)&As[nxt][rowA][colA]     = cvt4(na);
      *(uint2*)&Bs[nxt][rowB][colB]     = cvt4(nw0);
      *(uint2*)&Bs[nxt][rowB][colB + 4] = cvt4(nw1);
      __syncthreads();
    }
  }

  const int col = ln & 15, rb = (ln >> 4) * 4;
#pragma unroll
  for (int tn = 0; tn < 2; tn++)
#pragma unroll
    for (int j = 0; j < 4; j++) {
      int r = m0 + mh + rb + j, c = n0 + nh + tn * 16 + col;
      float val = acc[tn][j];
      if (isEf) {
        efh[(size_t)r * Hq + c] =
            (__bf16)__builtin_amdgcn_exp2f(val * TANH_SCALE);
      } else {
        decfh[(size_t)r * Hq + c] =
            (__bf16)__builtin_amdgcn_exp2f((val + bd[c]) * TANH_SCALE);
      }
    }
}

// ---------------- fused AB + single-wave scan (r26 structure) -----------------
// 1032 blocks: 0..1023 = AB tiles, 1024..1031 = scan (1 wave, no barriers).
// AB inner loop unrolled x8: batched LDS b64 reads + halved scalar-load issue.
__global__ __launch_bounds__(256, 4) void abscan_kernel(
    const __bf16* __restrict__ efh, const __bf16* __restrict__ decfh,
    const float* __restrict__ vvec, const float* __restrict__ w1g,
    const float* __restrict__ emask, const float* __restrict__ cov0,
    const float* __restrict__ dmask,
    float2* __restrict__ ab,
    float* __restrict__ out_attn, float* __restrict__ out_covf,
    float* __restrict__ lacc, unsigned* __restrict__ cnt)
{
  __shared__ double smem_raw[4808];           // 38464 B
  const int bid = blockIdx.x;
  const int tid = threadIdx.x;

  if (bid < 1024) {
    // -------- AB tile --------
    unsigned short (*efs)[780] = (unsigned short(*)[780])smem_raw;
    unsigned short (*dts)[776] = (unsigned short(*)[776])((char*)smem_raw + 24960);
    float (*part)[2]           = (float(*)[2])((char*)smem_raw + 37376);
    const int b = bid & 7;
    const int r = bid >> 3;                   // 0..127
    const int kchunk = r & 7;
    const int tt0 = kchunk * TT;
    const int st0 = (r >> 3) * ST;

    for (int i = tid; i < ST * 192; i += 256) {
      int row = i / 192, c = (i % 192) * 4;
      *(uint2*)&efs[row][c] =
          *(const uint2*)(efh + (size_t)(b * Sq + st0 + row) * Hq + c);
    }
    for (int i = tid; i < TT * 192; i += 256) {
      int row = i / 192, c = (i % 192) * 4;
      *(uint2*)&dts[row][c] =
          *(const uint2*)(decfh + (size_t)(b * Tq + tt0 + row) * Hq + c);
    }
    __syncthreads();

    const int hh = tid >> 7;
    const int pid = tid & 127;
    const int tl = pid >> 4, sl = pid & 15;
    const int hbase = hh * 384;
    const int hbu = __builtin_amdgcn_readfirstlane(hbase);
    const float* vp  = vvec + hbu;
    const float* w1p = w1g + hbu;

    float A = 0.f, B = 0.f;
#define BLO(x) __uint_as_float((x) << 16)
#define BHI(x) __uint_as_float((x) & 0xFFFF0000u)
#pragma unroll 2
    for (int j = 0; j < 384; j += 8) {
      // batch the LDS reads (4 x b64) and scalar streams (2 x dwordx4 each)
      uint2 eu0 = *(const uint2*)&efs[sl][hbase + j];
      uint2 eu1 = *(const uint2*)&efs[sl][hbase + j + 4];
      uint2 du0 = *(const uint2*)&dts[tl][hbase + j];
      uint2 du1 = *(const uint2*)&dts[tl][hbase + j + 4];
      f32x4 v40 = *(const f32x4*)(vp + j);
      f32x4 v41 = *(const f32x4*)(vp + j + 4);
      f32x4 w10 = *(const f32x4*)(w1p + j);
      f32x4 w11 = *(const f32x4*)(w1p + j + 4);
      float e2[8];
      e2[0] = BLO(eu0.x) * BLO(du0.x);
      e2[1] = BHI(eu0.x) * BHI(du0.x);
      e2[2] = BLO(eu0.y) * BLO(du0.y);
      e2[3] = BHI(eu0.y) * BHI(du0.y);
      e2[4] = BLO(eu1.x) * BLO(du1.x);
      e2[5] = BHI(eu1.x) * BHI(du1.x);
      e2[6] = BLO(eu1.y) * BLO(du1.y);
      e2[7] = BHI(eu1.y) * BHI(du1.y);
#pragma unroll
      for (int e = 0; e < 8; e++) {
        float rr = __builtin_amdgcn_rcpf(1.f + e2[e]);
        float t0 = 1.f - 2.f * rr;
        float f1 = 1.f - t0 * t0;
        float vx = (e < 4) ? v40[e] : v41[e - 4];
        float wx = (e < 4) ? w10[e] : w11[e - 4];
        A += vx * t0;
        B += wx * f1;
      }
    }
#undef BLO
#undef BHI

    if (hh == 1) { part[pid][0] = A; part[pid][1] = B; }
    __syncthreads();
    if (hh == 0) {
      union { float2 f; unsigned long long u; } cv;
      cv.f.x = A + part[pid][0];
      cv.f.y = B + part[pid][1];
      __hip_atomic_store(
          (unsigned long long*)&ab[(size_t)(b * Tq + tt0 + tl) * Sq + st0 + sl],
          cv.u, __ATOMIC_RELAXED, __HIP_MEMORY_SCOPE_AGENT);
    }
    __syncthreads();   // drains ab stores (vmcnt(0) pre-barrier)
    if (tid == 0)
      __hip_atomic_fetch_add(&cnt[b * 8 + kchunk], 1u,
                             __ATOMIC_RELAXED, __HIP_MEMORY_SCOPE_AGENT);
  } else {
    // -------- single-wave scan (batch b), r26-proven --------
    if (tid >= 64) return;
    const int b = bid - 1024;
    const int ln = tid;
    float dm = dmask[b * Tq + ln];
    float cov[4], em[4], E[4];
    float lp = 0.f;
#pragma unroll
    for (int i = 0; i < 4; i++) {
      cov[i] = cov0[b * Sq + ln + 64 * i];
      em[i]  = emask[b * Sq + ln + 64 * i];
    }
    const unsigned long long* P =
        (const unsigned long long*)(ab + (size_t)b * Tq * Sq + ln);
    union U64 { unsigned long long u; float2 f; };
    U64 cv0[4], cv1[4];

    for (int kc = 0; kc < 8; kc++) {
      unsigned c;
      do {
        c = __hip_atomic_load(&cnt[b * 8 + kc],
                              __ATOMIC_RELAXED, __HIP_MEMORY_SCOPE_AGENT);
      } while (__builtin_amdgcn_readfirstlane(c) < 16u);

      const int tb = kc * 8;
#pragma unroll
      for (int i = 0; i < 4; i++)
        cv0[i].u = __hip_atomic_load(P + (size_t)tb * Sq + 64 * i,
                                     __ATOMIC_RELAXED, __HIP_MEMORY_SCOPE_AGENT);
#pragma unroll
      for (int i = 0; i < 4; i++)
        cv1[i].u = __hip_atomic_load(P + (size_t)(tb + 1) * Sq + 64 * i,
                                     __ATOMIC_RELAXED, __HIP_MEMORY_SCOPE_AGENT);

#pragma unroll
      for (int j = 0; j < 8; j++) {
        const int t = tb + j;
        float s4 = 0.f;
#pragma unroll
        for (int i = 0; i < 4; i++) {
          float sc = cv0[i].f.x + cov[i] * cv0[i].f.y;
          E[i] = __builtin_amdgcn_exp2f(sc * LOG2E) * em[i];
          s4 += E[i];
        }
#pragma unroll
        for (int i = 0; i < 4; i++) {
          cv0[i] = cv1[i];
          if (j < 6)
            cv1[i].u = __hip_atomic_load(P + (size_t)(t + 2) * Sq + 64 * i,
                                         __ATOMIC_RELAXED, __HIP_MEMORY_SCOPE_AGENT);
        }
        float Z = wave64_sum(s4);
        float invZ = __builtin_amdgcn_rcpf(Z);
        float dmt = __shfl(dm, t);
#pragma unroll
        for (int i = 0; i < 4; i++) {
          float at = E[i] * invZ;
          lp += fminf(at, cov[i]) * dmt;
          cov[i] += at;
          out_attn[(size_t)(b * Tq + t) * Sq + ln + 64 * i] = at;  // plain store
        }
      }
    }

#pragma unroll
    for (int i = 0; i < 4; i++)
      out_covf[b * Sq + ln + 64 * i] = cov[i];
    float wl = wave64_sum(lp);
    if (ln == 0) atomicAdd(lacc, wl);
  }
}

// ---------------- deferred ht = attn @ enc + loss finalize (r18-proven) -------
__global__ __launch_bounds__(256) void ht_kernel(
    const float* __restrict__ attn, const float* __restrict__ enc,
    const float* __restrict__ dmask, const float* __restrict__ lacc,
    float* __restrict__ out_ht, float* __restrict__ out_loss)
{
  __shared__ float lat[Sq][8];
  __shared__ float r4[4];
  int bid = blockIdx.x;
  int b = bid / 24, r = bid % 24, tc = r / 3, hc = r % 3;
  int tid = threadIdx.x;
  int h = hc * 256 + tid;
#pragma unroll
  for (int tt = 0; tt < 8; tt++)
    lat[tid][tt] = attn[(size_t)(b * Tq + tc * 8 + tt) * Sq + tid];
  __syncthreads();

  float acc[8] = {};
  const float* ep = enc + (size_t)(b * Sq) * Hq + h;
  for (int sb = 0; sb < Sq; sb += 8) {
    float e[8];
#pragma unroll
    for (int u = 0; u < 8; u++) e[u] = ep[(size_t)(sb + u) * Hq];
#pragma unroll
    for (int u = 0; u < 8; u++) {
      f32x4 a0 = *(const f32x4*)&lat[sb + u][0];
      f32x4 a1 = *(const f32x4*)&lat[sb + u][4];
      acc[0] += a0[0] * e[u]; acc[1] += a0[1] * e[u];
      acc[2] += a0[2] * e[u]; acc[3] += a0[3] * e[u];
      acc[4] += a1[0] * e[u]; acc[5] += a1[1] * e[u];
      acc[6] += a1[2] * e[u]; acc[7] += a1[3] * e[u];
    }
  }
#pragma unroll
  for (int tt = 0; tt < 8; tt++)
    out_ht[(size_t)(b * Tq + tc * 8 + tt) * Hq + h] = acc[tt];

  if (blockIdx.x == 0) {
    float s = 0.f;
    for (int i = tid; i < Bq * Tq; i += 256) s += dmask[i];
#pragma unroll
    for (int off = 32; off; off >>= 1) s += __shfl_xor(s, off);
    int w = tid >> 6, ln = tid & 63;
    if (ln == 0) r4[w] = s;
    __syncthreads();
    if (tid == 0) out_loss[0] = lacc[0] / (r4[0] + r4[1] + r4[2] + r4[3]);
  }
}

extern "C" void kernel_launch(void* const* d_in, const int* in_sizes, int n_in,
                              void* d_out, int out_size, void* d_ws, size_t ws_size,
                              hipStream_t stream) {
  const float* dec   = (const float*)d_in[0];   // [8,64,768]
  const float* dmask = (const float*)d_in[1];   // [8,64]
  const float* enc   = (const float*)d_in[2];   // [8,256,768]
  const float* emask = (const float*)d_in[3];   // [8,256]
  const float* cov0  = (const float*)d_in[4];   // [8,256]
  const float* Wh    = (const float*)d_in[5];   // [768,768]
  const float* Wd    = (const float*)d_in[6];   // [768,768]
  const float* bd    = (const float*)d_in[7];   // [768]
  const float* wc    = (const float*)d_in[8];   // [768]
  const float* vv    = (const float*)d_in[9];   // [768]
  float* out = (float*)d_out;

  char* ws = (char*)d_ws;
  __bf16*   efh   = (__bf16*)ws;                 // 3145728 B
  __bf16*   decfh = (__bf16*)(ws + 3145728);     // 786432 B
  float2*   ab    = (float2*)(ws + 3932160);     // 1048576 B
  float*    w1g   = (float*)(ws + 4980736);      // 3072 B
  float*    lacc  = (float*)(ws + 4983808);      // 4 B
  unsigned* cnt   = (unsigned*)(ws + 4983872);   // 256 B

  const size_t OFF_ATTN = (size_t)Bq * Tq * Hq;             // 393216
  const size_t OFF_LOSS = OFF_ATTN + (size_t)Bq * Tq * Sq;  // 524288
  const size_t OFF_COV  = OFF_LOSS + 1;                     // 524289

  proj_kernel<<<960, 256, 0, stream>>>(enc, dec, Wh, Wd, bd, wc, vv,
                                       efh, decfh, w1g, lacc, cnt);
  abscan_kernel<<<1032, 256, 0, stream>>>(efh, decfh, vv, w1g, emask, cov0,
                                          dmask, ab,
                                          out + OFF_ATTN, out + OFF_COV,
                                          lacc, cnt);
  ht_kernel<<<192, 256, 0, stream>>>(out + OFF_ATTN, enc, dmask, lacc,
                                     out, out + OFF_LOSS);
}

// Round 29
// 75.298 us; speedup vs baseline: 1.1241x; 1.0731x over previous
//
#include <hip/hip_runtime.h>

#define Bq 8
#define Tq 64
#define Sq 256
#define Hq 768
#define TT 8
#define ST 8

typedef float f32x4 __attribute__((ext_vector_type(4)));
typedef __bf16 bf16x8 __attribute__((ext_vector_type(8)));

#define TANH_SCALE 2.885390081777927f   // 2*log2(e): exp2(u*TS) = e^{2u}
#define LOG2E 1.4426950408889634f

// ---- DPP reduction -----------------------------------------------------------
template <int Ctrl, int Rmask>
__device__ __forceinline__ float dpp_add_f(float v) {
  int t = __builtin_amdgcn_update_dpp(0, __float_as_int(v), Ctrl, Rmask, 0xF, true);
  return v + __int_as_float(t);
}
__device__ __forceinline__ float wave64_sum(float v) {
  v = dpp_add_f<0xB1, 0xF>(v);
  v = dpp_add_f<0x4E, 0xF>(v);
  v = dpp_add_f<0x141, 0xF>(v);
  v = dpp_add_f<0x140, 0xF>(v);
  v = dpp_add_f<0x142, 0xA>(v);
  v = dpp_add_f<0x143, 0xC>(v);
  return __int_as_float(__builtin_amdgcn_readlane(__float_as_int(v), 63));
}

__device__ __forceinline__ uint2 cvt4(f32x4 v) {
  union { __bf16 h[4]; uint2 u; } t;
  t.h[0] = (__bf16)v[0]; t.h[1] = (__bf16)v[1];
  t.h[2] = (__bf16)v[2]; t.h[3] = (__bf16)v[3];
  return t.u;
}

// ---------------- projection GEMMs (r23-proven, ~12us) ------------------------
__global__ __launch_bounds__(256, 4) void proj_kernel(
    const float* __restrict__ enc, const float* __restrict__ dec,
    const float* __restrict__ Wh, const float* __restrict__ Wd,
    const float* __restrict__ bd,
    const float* __restrict__ wcvec, const float* __restrict__ vvec,
    __bf16* __restrict__ efh, __bf16* __restrict__ decfh,
    float* __restrict__ w1g, float* __restrict__ lacc,
    unsigned* __restrict__ cnt)
{
  {
    int gidx = blockIdx.x * 256 + threadIdx.x;
    if (gidx < Hq) w1g[gidx] = vvec[gidx] * wcvec[gidx];
    if (gidx < 64) cnt[gidx] = 0u;
    if (gidx == 0) lacc[0] = 0.f;
  }

  __shared__ unsigned short As[2][32][40];
  __shared__ unsigned short Bs[2][64][40];

  int bid = blockIdx.x;
  const float* A; const float* W; bool isEf;
  int bm, bn;
  if (bid < 768) {
    A = enc; W = Wh; isEf = true;
    bm = bid % 64; bn = bid / 64;               // XCD affinity via bm%8
  } else {
    bid -= 768;
    A = dec; W = Wd; isEf = false;
    bm = bid % 16; bn = bid / 16;
  }
  const int m0 = bm * 32, n0 = bn * 64;

  const int ti = threadIdx.x;
  const int rowA = ti >> 3, colA = (ti & 7) * 4;
  const int rowB = ti >> 2, colB = (ti & 3) * 8;
  const float* pa = A + (size_t)(m0 + rowA) * Hq + colA;
  const float* pw = W + (size_t)(n0 + rowB) * Hq + colB;

  {
    f32x4 a0 = *(const f32x4*)pa;
    f32x4 w0 = *(const f32x4*)pw, w1 = *(const f32x4*)(pw + 4);
    *(uint2*)&As[0][rowA][colA]     = cvt4(a0);
    *(uint2*)&Bs[0][rowB][colB]     = cvt4(w0);
    *(uint2*)&Bs[0][rowB][colB + 4] = cvt4(w1);
  }
  __syncthreads();

  const int w = ti >> 6, ln = ti & 63;
  const int mh = (w >> 1) * 16, nh = (w & 1) * 32;
  const int rsel = ln & 15, kofe = (ln >> 4) * 8;

  f32x4 acc[2] = {};
  for (int k = 0; k < 24; k++) {
    f32x4 na, nw0, nw1;
    if (k < 23) {
      na  = *(const f32x4*)(pa + (k + 1) * 32);
      nw0 = *(const f32x4*)(pw + (k + 1) * 32);
      nw1 = *(const f32x4*)(pw + (k + 1) * 32 + 4);
    }
    const int cur = k & 1;
    bf16x8 af = *(const bf16x8*)&As[cur][mh + rsel][kofe];
    bf16x8 b0 = *(const bf16x8*)&Bs[cur][nh + rsel][kofe];
    bf16x8 b1 = *(const bf16x8*)&Bs[cur][nh + 16 + rsel][kofe];
    acc[0] = __builtin_amdgcn_mfma_f32_16x16x32_bf16(af, b0, acc[0], 0, 0, 0);
    acc[1] = __builtin_amdgcn_mfma_f32_16x16x32_bf16(af, b1, acc[1], 0, 0, 0);
    if (k < 23) {
      const int nxt = cur ^ 1;
      *(uint2*)&As[nxt][rowA][colA]     = cvt4(na);
      *(uint2*)&Bs[nxt][rowB][colB]     = cvt4(nw0);
      *(uint2*)&Bs[nxt][rowB][colB + 4] = cvt4(nw1);
      __syncthreads();
    }
  }

  const int col = ln & 15, rb = (ln >> 4) * 4;
#pragma unroll
  for (int tn = 0; tn < 2; tn++)
#pragma unroll
    for (int j = 0; j < 4; j++) {
      int r = m0 + mh + rb + j, c = n0 + nh + tn * 16 + col;
      float val = acc[tn][j];
      if (isEf) {
        efh[(size_t)r * Hq + c] =
            (__bf16)__builtin_amdgcn_exp2f(val * TANH_SCALE);
      } else {
        decfh[(size_t)r * Hq + c] =
            (__bf16)__builtin_amdgcn_exp2f((val + bd[c]) * TANH_SCALE);
      }
    }
}

// ---------------- fused AB + single-wave scan ---------------------------------
// 2056 blocks: 0..2047 = AB tiles (ST=8, chunk-major bid order -> chunks
// complete staggered across two co-residency generations), 2048..2055 = scan.
// LDS 26.2KB -> 6 blocks/CU (24 waves/CU). cnt[b*8+kc] target = 32 tiles.
// Handoffs: relaxed agent atomics (r20-proven); scan attn = plain stores.
__global__ __launch_bounds__(256, 6) void abscan_kernel(
    const __bf16* __restrict__ efh, const __bf16* __restrict__ decfh,
    const float* __restrict__ vvec, const float* __restrict__ w1g,
    const float* __restrict__ emask, const float* __restrict__ cov0,
    const float* __restrict__ dmask,
    float2* __restrict__ ab,
    float* __restrict__ out_attn, float* __restrict__ out_covf,
    float* __restrict__ lacc, unsigned* __restrict__ cnt)
{
  __shared__ double smem_raw[3280];           // 26240 B
  const int bid = blockIdx.x;
  const int tid = threadIdx.x;

  if (bid < 2048) {
    // -------- AB tile: 8t x 8s, 4 h-quarters --------
    unsigned short (*efs)[772] = (unsigned short(*)[772])smem_raw;                  // 12352 B
    unsigned short (*dts)[772] = (unsigned short(*)[772])((char*)smem_raw + 12352); // 12352 B
    float (*part)[64][2]       = (float(*)[64][2])((char*)smem_raw + 24704);        // 1536 B
    const int kchunk = bid >> 8;              // chunk-major: staggered completion
    const int b = (bid >> 5) & 7;
    const int stile = bid & 31;
    const int tt0 = kchunk * TT;
    const int st0 = stile * ST;

    for (int i = tid; i < ST * 192; i += 256) {
      int row = i / 192, c = (i % 192) * 4;
      *(uint2*)&efs[row][c] =
          *(const uint2*)(efh + (size_t)(b * Sq + st0 + row) * Hq + c);
    }
    for (int i = tid; i < TT * 192; i += 256) {
      int row = i / 192, c = (i % 192) * 4;
      *(uint2*)&dts[row][c] =
          *(const uint2*)(decfh + (size_t)(b * Tq + tt0 + row) * Hq + c);
    }
    __syncthreads();

    const int hh = tid >> 6;                  // wave 0..3 = h-quarter
    const int pid = tid & 63;                 // 64 (t,s) pairs
    const int tl = pid >> 3, sl = pid & 7;
    const int hbase = hh * 192;
    const int hbu = __builtin_amdgcn_readfirstlane(hbase);
    const float* vp  = vvec + hbu;
    const float* w1p = w1g + hbu;

    float A = 0.f, B = 0.f;
#define BLO(x) __uint_as_float((x) << 16)
#define BHI(x) __uint_as_float((x) & 0xFFFF0000u)
#pragma unroll 2
    for (int j = 0; j < 192; j += 8) {
      uint2 eu0 = *(const uint2*)&efs[sl][hbase + j];
      uint2 eu1 = *(const uint2*)&efs[sl][hbase + j + 4];
      uint2 du0 = *(const uint2*)&dts[tl][hbase + j];
      uint2 du1 = *(const uint2*)&dts[tl][hbase + j + 4];
      f32x4 v40 = *(const f32x4*)(vp + j);
      f32x4 v41 = *(const f32x4*)(vp + j + 4);
      f32x4 w10 = *(const f32x4*)(w1p + j);
      f32x4 w11 = *(const f32x4*)(w1p + j + 4);
      float e2[8];
      e2[0] = BLO(eu0.x) * BLO(du0.x);
      e2[1] = BHI(eu0.x) * BHI(du0.x);
      e2[2] = BLO(eu0.y) * BLO(du0.y);
      e2[3] = BHI(eu0.y) * BHI(du0.y);
      e2[4] = BLO(eu1.x) * BLO(du1.x);
      e2[5] = BHI(eu1.x) * BHI(du1.x);
      e2[6] = BLO(eu1.y) * BLO(du1.y);
      e2[7] = BHI(eu1.y) * BHI(du1.y);
#pragma unroll
      for (int e = 0; e < 8; e++) {
        float rr = __builtin_amdgcn_rcpf(1.f + e2[e]);
        float t0 = 1.f - 2.f * rr;
        float f1 = 1.f - t0 * t0;
        float vx = (e < 4) ? v40[e] : v41[e - 4];
        float wx = (e < 4) ? w10[e] : w11[e - 4];
        A += vx * t0;
        B += wx * f1;
      }
    }
#undef BLO
#undef BHI

    if (hh != 0) { part[hh - 1][pid][0] = A; part[hh - 1][pid][1] = B; }
    __syncthreads();
    if (hh == 0) {
      union { float2 f; unsigned long long u; } cv;
      cv.f.x = A + part[0][pid][0] + part[1][pid][0] + part[2][pid][0];
      cv.f.y = B + part[0][pid][1] + part[1][pid][1] + part[2][pid][1];
      __hip_atomic_store(
          (unsigned long long*)&ab[(size_t)(b * Tq + tt0 + tl) * Sq + st0 + sl],
          cv.u, __ATOMIC_RELAXED, __HIP_MEMORY_SCOPE_AGENT);
    }
    __syncthreads();   // drains ab stores (vmcnt(0) pre-barrier)
    if (tid == 0)
      __hip_atomic_fetch_add(&cnt[b * 8 + kchunk], 1u,
                             __ATOMIC_RELAXED, __HIP_MEMORY_SCOPE_AGENT);
  } else {
    // -------- single-wave scan (batch b), r26-proven --------
    if (tid >= 64) return;
    const int b = bid - 2048;
    const int ln = tid;
    float dm = dmask[b * Tq + ln];
    float cov[4], em[4], E[4];
    float lp = 0.f;
#pragma unroll
    for (int i = 0; i < 4; i++) {
      cov[i] = cov0[b * Sq + ln + 64 * i];
      em[i]  = emask[b * Sq + ln + 64 * i];
    }
    const unsigned long long* P =
        (const unsigned long long*)(ab + (size_t)b * Tq * Sq + ln);
    union U64 { unsigned long long u; float2 f; };
    U64 cv0[4], cv1[4];

    for (int kc = 0; kc < 8; kc++) {
      unsigned c;
      do {
        c = __hip_atomic_load(&cnt[b * 8 + kc],
                              __ATOMIC_RELAXED, __HIP_MEMORY_SCOPE_AGENT);
      } while (__builtin_amdgcn_readfirstlane(c) < 32u);

      const int tb = kc * 8;
#pragma unroll
      for (int i = 0; i < 4; i++)
        cv0[i].u = __hip_atomic_load(P + (size_t)tb * Sq + 64 * i,
                                     __ATOMIC_RELAXED, __HIP_MEMORY_SCOPE_AGENT);
#pragma unroll
      for (int i = 0; i < 4; i++)
        cv1[i].u = __hip_atomic_load(P + (size_t)(tb + 1) * Sq + 64 * i,
                                     __ATOMIC_RELAXED, __HIP_MEMORY_SCOPE_AGENT);

#pragma unroll
      for (int j = 0; j < 8; j++) {
        const int t = tb + j;
        float s4 = 0.f;
#pragma unroll
        for (int i = 0; i < 4; i++) {
          float sc = cv0[i].f.x + cov[i] * cv0[i].f.y;
          E[i] = __builtin_amdgcn_exp2f(sc * LOG2E) * em[i];
          s4 += E[i];
        }
#pragma unroll
        for (int i = 0; i < 4; i++) {
          cv0[i] = cv1[i];
          if (j < 6)
            cv1[i].u = __hip_atomic_load(P + (size_t)(t + 2) * Sq + 64 * i,
                                         __ATOMIC_RELAXED, __HIP_MEMORY_SCOPE_AGENT);
        }
        float Z = wave64_sum(s4);
        float invZ = __builtin_amdgcn_rcpf(Z);
        float dmt = __shfl(dm, t);
#pragma unroll
        for (int i = 0; i < 4; i++) {
          float at = E[i] * invZ;
          lp += fminf(at, cov[i]) * dmt;
          cov[i] += at;
          out_attn[(size_t)(b * Tq + t) * Sq + ln + 64 * i] = at;  // plain store
        }
      }
    }

#pragma unroll
    for (int i = 0; i < 4; i++)
      out_covf[b * Sq + ln + 64 * i] = cov[i];
    float wl = wave64_sum(lp);
    if (ln == 0) atomicAdd(lacc, wl);
  }
}

// ---------------- deferred ht = attn @ enc + loss finalize (r18-proven) -------
__global__ __launch_bounds__(256) void ht_kernel(
    const float* __restrict__ attn, const float* __restrict__ enc,
    const float* __restrict__ dmask, const float* __restrict__ lacc,
    float* __restrict__ out_ht, float* __restrict__ out_loss)
{
  __shared__ float lat[Sq][8];
  __shared__ float r4[4];
  int bid = blockIdx.x;
  int b = bid / 24, r = bid % 24, tc = r / 3, hc = r % 3;
  int tid = threadIdx.x;
  int h = hc * 256 + tid;
#pragma unroll
  for (int tt = 0; tt < 8; tt++)
    lat[tid][tt] = attn[(size_t)(b * Tq + tc * 8 + tt) * Sq + tid];
  __syncthreads();

  float acc[8] = {};
  const float* ep = enc + (size_t)(b * Sq) * Hq + h;
  for (int sb = 0; sb < Sq; sb += 8) {
    float e[8];
#pragma unroll
    for (int u = 0; u < 8; u++) e[u] = ep[(size_t)(sb + u) * Hq];
#pragma unroll
    for (int u = 0; u < 8; u++) {
      f32x4 a0 = *(const f32x4*)&lat[sb + u][0];
      f32x4 a1 = *(const f32x4*)&lat[sb + u][4];
      acc[0] += a0[0] * e[u]; acc[1] += a0[1] * e[u];
      acc[2] += a0[2] * e[u]; acc[3] += a0[3] * e[u];
      acc[4] += a1[0] * e[u]; acc[5] += a1[1] * e[u];
      acc[6] += a1[2] * e[u]; acc[7] += a1[3] * e[u];
    }
  }
#pragma unroll
  for (int tt = 0; tt < 8; tt++)
    out_ht[(size_t)(b * Tq + tc * 8 + tt) * Hq + h] = acc[tt];

  if (blockIdx.x == 0) {
    float s = 0.f;
    for (int i = tid; i < Bq * Tq; i += 256) s += dmask[i];
#pragma unroll
    for (int off = 32; off; off >>= 1) s += __shfl_xor(s, off);
    int w = tid >> 6, ln = tid & 63;
    if (ln == 0) r4[w] = s;
    __syncthreads();
    if (tid == 0) out_loss[0] = lacc[0] / (r4[0] + r4[1] + r4[2] + r4[3]);
  }
}

extern "C" void kernel_launch(void* const* d_in, const int* in_sizes, int n_in,
                              void* d_out, int out_size, void* d_ws, size_t ws_size,
                              hipStream_t stream) {
  const float* dec   = (const float*)d_in[0];   // [8,64,768]
  const float* dmask = (const float*)d_in[1];   // [8,64]
  const float* enc   = (const float*)d_in[2];   // [8,256,768]
  const float* emask = (const float*)d_in[3];   // [8,256]
  const float* cov0  = (const float*)d_in[4];   // [8,256]
  const float* Wh    = (const float*)d_in[5];   // [768,768]
  const float* Wd    = (const float*)d_in[6];   // [768,768]
  const float* bd    = (const float*)d_in[7];   // [768]
  const float* wc    = (const float*)d_in[8];   // [768]
  const float* vv    = (const float*)d_in[9];   // [768]
  float* out = (float*)d_out;

  char* ws = (char*)d_ws;
  __bf16*   efh   = (__bf16*)ws;                 // 3145728 B
  __bf16*   decfh = (__bf16*)(ws + 3145728);     // 786432 B
  float2*   ab    = (float2*)(ws + 3932160);     // 1048576 B
  float*    w1g   = (float*)(ws + 4980736);      // 3072 B
  float*    lacc  = (float*)(ws + 4983808);      // 4 B
  unsigned* cnt   = (unsigned*)(ws + 4983872);   // 256 B

  const size_t OFF_ATTN = (size_t)Bq * Tq * Hq;             // 393216
  const size_t OFF_LOSS = OFF_ATTN + (size_t)Bq * Tq * Sq;  // 524288
  const size_t OFF_COV  = OFF_LOSS + 1;                     // 524289

  proj_kernel<<<960, 256, 0, stream>>>(enc, dec, Wh, Wd, bd, wc, vv,
                                       efh, decfh, w1g, lacc, cnt);
  abscan_kernel<<<2056, 256, 0, stream>>>(efh, decfh, vv, w1g, emask, cov0,
                                          dmask, ab,
                                          out + OFF_ATTN, out + OFF_COV,
                                          lacc, cnt);
  ht_kernel<<<192, 256, 0, stream>>>(out + OFF_ATTN, enc, dmask, lacc,
                                     out, out + OFF_LOSS);
}